// Round 2
// baseline (961.963 us; speedup 1.0000x reference)
//
#include <hip/hip_runtime.h>
#include <cstdint>
#include <cstddef>

// ---------------- problem constants ----------------
#define L_SEQ   4096
#define DIM_IN  1024
#define DI      1536
#define BATCH   4
#define RPB     L_SEQ                 // rows per batch element

typedef unsigned short u16;
typedef __attribute__((ext_vector_type(8))) short  short8;   // 8 bf16 = 4 VGPRs
typedef __attribute__((ext_vector_type(4))) float  f32x4;

struct __align__(8) u16x4 { u16 x, y, z, w; };

// ---------------- helpers ----------------
__device__ __forceinline__ float bf2f(u16 u) {
  union { unsigned int i; float f; } v; v.i = ((unsigned int)u) << 16; return v.f;
}
__device__ __forceinline__ u16 f2bf(float f) {
  union { float f; unsigned int i; } v; v.f = f;
  unsigned int x = v.i;
  return (u16)((x + 0x7fffu + ((x >> 16) & 1u)) >> 16);   // RNE
}
__device__ __forceinline__ float siluf_(float v) {
  return v / (1.0f + __expf(-v));
}
__device__ __forceinline__ float softplusf_(float v) {
  return fmaxf(v, 0.0f) + log1pf(__expf(-fabsf(v)));
}
__device__ __forceinline__ void gload16(const void* g, void* l) {
  __builtin_amdgcn_global_load_lds((const __attribute__((address_space(1))) void*)g,
                                   (__attribute__((address_space(3))) void*)l,
                                   16, 0, 0);
}

// ---------------- fp32 -> bf16 convert ----------------
__global__ void to_bf16(const float* __restrict__ in, u16* __restrict__ out, int n4) {
  int i = blockIdx.x * blockDim.x + threadIdx.x;
  if (i >= n4) return;
  float4 v = ((const float4*)in)[i];
  u16x4 o;
  o.x = f2bf(v.x); o.y = f2bf(v.y); o.z = f2bf(v.z); o.w = f2bf(v.w);
  ((u16x4*)out)[i] = o;
}

// ---------------- bf16 MFMA GEMM, C = A(MxK) * Bt(NxK)^T ----------------
// m97 structure: 128x128 tile, BK=32, 4 waves 2x2, each wave 64x64 (4x4 of 16x16),
// global_load_lds width=16 staging, 2-barrier K-loop.
// EPI 0: plain fp32 C store (c_out, ld N)
// EPI 1: in_proj: col<DI -> bf16 x_inner e_bf_a[row*DI+col]
//                 col>=DI -> silu -> bf16 sz e_bf1[row*DI+col-DI]
// EPI 2: dt: dt=softplus(acc+e_v2[col]); a=exp(e_v1[col]*dt);
//        w = bf2f(e_bf2[row,col])*dt*a -> e_bf_a ; a -> e_bf1
template <int EPI>
__launch_bounds__(256, 2)
__global__ void gemm_bt(const u16* __restrict__ A, const u16* __restrict__ Bt,
                        float* __restrict__ c_out,
                        int N, int K,
                        u16* __restrict__ e_bf_a,
                        u16* __restrict__ e_bf1,
                        const u16* __restrict__ e_bf2,
                        const float* __restrict__ e_v1,
                        const float* __restrict__ e_v2) {
  __shared__ u16 Alds[128 * 32];   // 8 KB
  __shared__ u16 Blds[128 * 32];   // 8 KB

  const int tid  = threadIdx.x;
  const int wave = tid >> 6;
  const int lane = tid & 63;
  const int quad = lane >> 4;
  const int l16  = lane & 15;
  const int m0 = blockIdx.y * 128;
  const int n0 = blockIdx.x * 128;
  const int waveM = wave & 1;      // 2x2 wave grid
  const int waveN = wave >> 1;

  // staging: tile = 128 rows x 64 B = 512 chunks of 16B; wave w stages rows
  // [32w, 32w+32) via two pointers (r0, r0+16); lane's quarter q covers 16B.
  const int q  = lane & 3;
  const int r0 = wave * 32 + (lane >> 2);
  const size_t koff = (size_t)q * 8;

  const u16* Ap0 = A  + (size_t)(m0 + r0)      * K + koff;
  const u16* Ap1 = A  + (size_t)(m0 + r0 + 16) * K + koff;
  const u16* Bp0 = Bt + (size_t)(n0 + r0)      * K + koff;
  const u16* Bp1 = Bt + (size_t)(n0 + r0 + 16) * K + koff;
  u16* aseg0 = &Alds[(wave * 2 + 0) * 512];
  u16* aseg1 = &Alds[(wave * 2 + 1) * 512];
  u16* bseg0 = &Blds[(wave * 2 + 0) * 512];
  u16* bseg1 = &Blds[(wave * 2 + 1) * 512];

  f32x4 acc[4][4] = {};

  for (int k0 = 0; k0 < K; k0 += 32) {
    gload16(Ap0 + k0, aseg0);
    gload16(Ap1 + k0, aseg1);
    gload16(Bp0 + k0, bseg0);
    gload16(Bp1 + k0, bseg1);
    __syncthreads();

    short8 af[4], bf[4];
#pragma unroll
    for (int i = 0; i < 4; i++) {
      af[i] = *(const short8*)&Alds[(waveM * 64 + i * 16 + l16) * 32 + quad * 8];
      bf[i] = *(const short8*)&Blds[(waveN * 64 + i * 16 + l16) * 32 + quad * 8];
    }
#pragma unroll
    for (int mi = 0; mi < 4; mi++)
#pragma unroll
      for (int ni = 0; ni < 4; ni++)
        acc[mi][ni] = __builtin_amdgcn_mfma_f32_16x16x32_bf16(af[mi], bf[ni],
                                                              acc[mi][ni], 0, 0, 0);
    __syncthreads();
  }

  // epilogue: C/D layout col=lane&15, row=quad*4+reg (m89/m91-verified)
#pragma unroll
  for (int mi = 0; mi < 4; mi++) {
    const int rowBase = m0 + waveM * 64 + mi * 16 + quad * 4;
#pragma unroll
    for (int ni = 0; ni < 4; ni++) {
      const int gcol = n0 + waveN * 64 + ni * 16 + l16;
#pragma unroll
      for (int r = 0; r < 4; r++) {
        const float v = acc[mi][ni][r];
        const size_t row = (size_t)(rowBase + r);
        if constexpr (EPI == 0) {
          c_out[row * (size_t)N + gcol] = v;
        } else if constexpr (EPI == 1) {
          if (gcol < DI) {
            e_bf_a[row * DI + gcol] = f2bf(v);
          } else {
            e_bf1[row * DI + (gcol - DI)] = f2bf(siluf_(v));
          }
        } else {
          const float dt = softplusf_(v + e_v2[gcol]);
          const float a  = __expf(e_v1[gcol] * dt);
          const float xc = bf2f(e_bf2[row * DI + gcol]);
          e_bf_a[row * DI + gcol] = f2bf(xc * dt * a);
          e_bf1[row * DI + gcol] = f2bf(a);
        }
      }
    }
  }
}

// ---------------- depthwise conv1d(k=3,pad=1) + bias + SiLU (per batch) ----------
__global__ void conv_silu(const u16* __restrict__ xin, const float* __restrict__ cw,
                          const float* __restrict__ cb, u16* __restrict__ xconv_bf) {
  const int idx = blockIdx.x * blockDim.x + threadIdx.x;   // one thread = 4 channels
  const int c4 = (idx % (DI / 4)) * 4;
  const int l  = idx / (DI / 4);                           // 0..4095

  const size_t base = (size_t)l * DI + c4;
  u16x4 z4 = {0, 0, 0, 0};
  u16x4 x1 = *(const u16x4*)(xin + base);
  u16x4 x0 = (l > 0)       ? *(const u16x4*)(xin + base - DI) : z4;
  u16x4 x2 = (l < RPB - 1) ? *(const u16x4*)(xin + base + DI) : z4;

  const u16* p0 = (const u16*)&x0;
  const u16* p1 = (const u16*)&x1;
  const u16* p2 = (const u16*)&x2;
  u16x4 o;
  u16* po = (u16*)&o;
#pragma unroll
  for (int j = 0; j < 4; j++) {
    const int c = c4 + j;
    float v = fmaf(cw[c * 3 + 0], bf2f(p0[j]),
              fmaf(cw[c * 3 + 1], bf2f(p1[j]),
                   cw[c * 3 + 2] * bf2f(p2[j]))) + cb[c];
    po[j] = f2bf(siluf_(v));
  }
  *(u16x4*)&xconv_bf[base] = o;
}

// ---------------- chunked prefix scan over L (per batch; chunk=128, 32 chunks) ----
#define CHUNK 128
#define NCHUNK (RPB / CHUNK)   // 32

__global__ void scan_partial(const u16* __restrict__ w, float* __restrict__ partial) {
  const int c  = blockIdx.x * 256 + threadIdx.x;   // 0..1535
  const int ch = blockIdx.y;
  size_t base = (size_t)ch * CHUNK * DI + c;
  float s = 0.0f;
#pragma unroll 4
  for (int i = 0; i < CHUNK; i++) s += bf2f(w[base + (size_t)i * DI]);
  partial[(size_t)ch * DI + c] = s;
}

__global__ void scan_offsets(float* __restrict__ partial) {
  const int c = blockIdx.x * 256 + threadIdx.x;    // 0..1535
  float run = 0.0f;
  for (int ch = 0; ch < NCHUNK; ch++) {
    size_t p = (size_t)ch * DI + c;
    float v = partial[p];
    partial[p] = run;
    run += v;
  }
}

// NOTE: ybf aliases aexp (same index read-then-write per thread) — no __restrict__.
__global__ void scan_apply(const u16* __restrict__ w, const float* __restrict__ partial,
                           const u16* aexp, const u16* __restrict__ xconv,
                           const u16* __restrict__ sz, const float* __restrict__ Dp,
                           u16* ybf) {
  const int c  = blockIdx.x * 256 + threadIdx.x;
  const int ch = blockIdx.y;
  float run = partial[(size_t)ch * DI + c];
  const float dp = Dp[c];
  size_t base = (size_t)ch * CHUNK * DI + c;
  for (int i = 0; i < CHUNK; i++) {
    size_t p = base + (size_t)i * DI;
    float ae = bf2f(aexp[p]);             // read BEFORE the aliased write
    run += bf2f(w[p]);
    float y = run * ae + bf2f(xconv[p]) * dp;
    y *= bf2f(sz[p]);
    ybf[p] = f2bf(y);
  }
}

// ---------------- launcher ----------------
extern "C" void kernel_launch(void* const* d_in, const int* in_sizes, int n_in,
                              void* d_out, int out_size, void* d_ws, size_t ws_size,
                              hipStream_t stream) {
  const float* x      = (const float*)d_in[0];
  const float* W_in   = (const float*)d_in[1];   // (3072,1024)
  const float* W_out  = (const float*)d_in[2];   // (1024,1536)
  const float* conv_w = (const float*)d_in[3];   // (1536,1,3)
  const float* conv_b = (const float*)d_in[4];
  const float* dt_w   = (const float*)d_in[5];   // (1536,1536)
  const float* dt_b   = (const float*)d_in[6];
  const float* Avec   = (const float*)d_in[7];
  const float* Dp     = (const float*)d_in[8];
  float* out = (float*)d_out;
  char* ws = (char*)d_ws;

  // workspace layout (bytes, 256-aligned). total = 73,072,640
  const size_t WS_NEED = 73072640;
  if (ws_size < WS_NEED) return;   // diagnostic: absmax=2096 w/o crash => ws too small

  u16*   Win_bf   = (u16*)  (ws + 0);          //  6,291,456
  u16*   dtw_bf   = (u16*)  (ws + 6291456);    //  4,718,592
  u16*   Wout_bf  = (u16*)  (ws + 11010048);   //  3,145,728
  u16*   x_bf     = (u16*)  (ws + 14155776);   //  8,388,608   (4096x1024 bf16)
  u16*   xin_bf   = (u16*)  (ws + 22544384);   // 12,582,912   (4096x1536) [w aliases]
  u16*   sz_bf    = (u16*)  (ws + 35127296);   // 12,582,912
  u16*   xconv_bf = (u16*)  (ws + 47710208);   // 12,582,912
  u16*   aexp_bf  = (u16*)  (ws + 60293120);   // 12,582,912   [y aliases]
  float* part     = (float*)(ws + 72876032);   //    196,608   (32x1536 fp32)
  u16*   w_bf     = xin_bf;                    // alias: x_inner dead after conv
  u16*   y_bf     = aexp_bf;                   // alias: elementwise read-then-write

  // weights -> bf16 (once)
  to_bf16<<<3072, 256, 0, stream>>>(W_in,  Win_bf,  786432);
  to_bf16<<<2304, 256, 0, stream>>>(dt_w,  dtw_bf,  589824);
  to_bf16<<<1536, 256, 0, stream>>>(W_out, Wout_bf, 393216);

  for (int b = 0; b < BATCH; b++) {
    const float* xb   = x   + (size_t)b * RPB * DIM_IN;
    float*       outb = out + (size_t)b * RPB * DIM_IN;

    to_bf16<<<4096, 256, 0, stream>>>(xb, x_bf, 1048576);

    // in_proj GEMM (M=4096, N=3072, K=1024) + split epilogue
    gemm_bt<1><<<dim3(24, 32), 256, 0, stream>>>(x_bf, Win_bf, nullptr,
                                                 2 * DI, DIM_IN,
                                                 xin_bf, sz_bf, nullptr, nullptr, nullptr);
    // depthwise conv + SiLU
    conv_silu<<<6144, 256, 0, stream>>>(xin_bf, conv_w, conv_b, xconv_bf);

    // dt GEMM (M=4096, N=1536, K=1536) + softplus/exp/w epilogue
    gemm_bt<2><<<dim3(12, 32), 256, 0, stream>>>(xconv_bf, dtw_bf, nullptr,
                                                 DI, DI,
                                                 w_bf, aexp_bf, xconv_bf, Avec, dt_b);

    // chunked prefix scan + pointwise tail -> y bf16
    scan_partial<<<dim3(6, NCHUNK), 256, 0, stream>>>(w_bf, part);
    scan_offsets<<<6, 256, 0, stream>>>(part);
    scan_apply<<<dim3(6, NCHUNK), 256, 0, stream>>>(w_bf, part, aexp_bf,
                                                    xconv_bf, sz_bf, Dp, y_bf);

    // out_proj GEMM (M=4096, N=1024, K=1536) -> fp32 output
    gemm_bt<0><<<dim3(8, 32), 256, 0, stream>>>(y_bf, Wout_bf, outb,
                                                DIM_IN, DI,
                                                nullptr, nullptr, nullptr, nullptr, nullptr);
  }
}

// Round 3
// 623.107 us; speedup vs baseline: 1.5438x; 1.5438x over previous
//
#include <hip/hip_runtime.h>
#include <cstdint>
#include <cstddef>

// ---------------- problem constants ----------------
#define L_SEQ   4096
#define DIM_IN  1024
#define DI      1536
#define BATCH   4

typedef unsigned short u16;
typedef __attribute__((ext_vector_type(8))) short  short8;   // 8 bf16 = 4 VGPRs
typedef __attribute__((ext_vector_type(4))) float  f32x4;

struct __align__(8) u16x4 { u16 x, y, z, w; };

// ---------------- helpers ----------------
__device__ __forceinline__ float bf2f(u16 u) {
  union { unsigned int i; float f; } v; v.i = ((unsigned int)u) << 16; return v.f;
}
__device__ __forceinline__ u16 f2bf(float f) {
  union { float f; unsigned int i; } v; v.f = f;
  unsigned int x = v.i;
  return (u16)((x + 0x7fffu + ((x >> 16) & 1u)) >> 16);   // RNE
}
__device__ __forceinline__ float siluf_(float v) {
  return v / (1.0f + __expf(-v));
}
__device__ __forceinline__ float softplusf_(float v) {
  return fmaxf(v, 0.0f) + log1pf(__expf(-fabsf(v)));
}
__device__ __forceinline__ void gload16(const void* g, void* l) {
  __builtin_amdgcn_global_load_lds((const __attribute__((address_space(1))) void*)g,
                                   (__attribute__((address_space(3))) void*)l,
                                   16, 0, 0);
}

// ---------------- fp32 -> bf16 convert ----------------
__global__ void to_bf16(const float* __restrict__ in, u16* __restrict__ out, int n4) {
  int i = blockIdx.x * blockDim.x + threadIdx.x;
  if (i >= n4) return;
  float4 v = ((const float4*)in)[i];
  u16x4 o;
  o.x = f2bf(v.x); o.y = f2bf(v.y); o.z = f2bf(v.z); o.w = f2bf(v.w);
  ((u16x4*)out)[i] = o;
}

// ---------------- bf16 MFMA GEMM, C = A(MxK) * Bt(NxK)^T ----------------
// m97 structure: 128x128 tile, BK=32, 4 waves 2x2, each wave 64x64 (4x4 of 16x16),
// global_load_lds width=16 staging, 2-barrier K-loop.
// EPI 0: plain fp32 C store (c_out, ld N)
// EPI 1: in_proj: col<DI -> bf16 x_inner e_bf_a[row*DI+col]
//                 col>=DI -> silu -> bf16 sz e_bf1[row*DI+col-DI]
// EPI 2: dt: dt=softplus(acc+e_v2[col]); a=exp(e_v1[col]*dt);
//        w = bf2f(e_bf2[row,col])*dt*a -> e_bf_a ; a -> e_bf1
template <int EPI>
__launch_bounds__(256, 2)
__global__ void gemm_bt(const u16* __restrict__ A, const u16* __restrict__ Bt,
                        float* __restrict__ c_out,
                        int N, int K,
                        u16* __restrict__ e_bf_a,
                        u16* __restrict__ e_bf1,
                        const u16* __restrict__ e_bf2,
                        const float* __restrict__ e_v1,
                        const float* __restrict__ e_v2) {
  __shared__ u16 Alds[128 * 32];   // 8 KB
  __shared__ u16 Blds[128 * 32];   // 8 KB

  const int tid  = threadIdx.x;
  const int wave = tid >> 6;
  const int lane = tid & 63;
  const int quad = lane >> 4;
  const int l16  = lane & 15;
  const int m0 = blockIdx.y * 128;
  const int n0 = blockIdx.x * 128;
  const int waveM = wave & 1;      // 2x2 wave grid
  const int waveN = wave >> 1;

  // staging: tile = 128 rows x 64 B = 512 chunks of 16B; wave w stages rows
  // [32w, 32w+32) via two pointers (r0, r0+16); lane's quarter q covers 16B.
  const int q  = lane & 3;
  const int r0 = wave * 32 + (lane >> 2);
  const size_t koff = (size_t)q * 8;

  const u16* Ap0 = A  + (size_t)(m0 + r0)      * K + koff;
  const u16* Ap1 = A  + (size_t)(m0 + r0 + 16) * K + koff;
  const u16* Bp0 = Bt + (size_t)(n0 + r0)      * K + koff;
  const u16* Bp1 = Bt + (size_t)(n0 + r0 + 16) * K + koff;
  u16* aseg0 = &Alds[(wave * 2 + 0) * 512];
  u16* aseg1 = &Alds[(wave * 2 + 1) * 512];
  u16* bseg0 = &Blds[(wave * 2 + 0) * 512];
  u16* bseg1 = &Blds[(wave * 2 + 1) * 512];

  f32x4 acc[4][4] = {};

  for (int k0 = 0; k0 < K; k0 += 32) {
    gload16(Ap0 + k0, aseg0);
    gload16(Ap1 + k0, aseg1);
    gload16(Bp0 + k0, bseg0);
    gload16(Bp1 + k0, bseg1);
    __syncthreads();

    short8 af[4], bf[4];
#pragma unroll
    for (int i = 0; i < 4; i++) {
      af[i] = *(const short8*)&Alds[(waveM * 64 + i * 16 + l16) * 32 + quad * 8];
      bf[i] = *(const short8*)&Blds[(waveN * 64 + i * 16 + l16) * 32 + quad * 8];
    }
#pragma unroll
    for (int mi = 0; mi < 4; mi++)
#pragma unroll
      for (int ni = 0; ni < 4; ni++)
        acc[mi][ni] = __builtin_amdgcn_mfma_f32_16x16x32_bf16(af[mi], bf[ni],
                                                              acc[mi][ni], 0, 0, 0);
    __syncthreads();
  }

  // epilogue: C/D layout col=lane&15, row=quad*4+reg (m89/m91-verified)
#pragma unroll
  for (int mi = 0; mi < 4; mi++) {
    const int rowBase = m0 + waveM * 64 + mi * 16 + quad * 4;
#pragma unroll
    for (int ni = 0; ni < 4; ni++) {
      const int gcol = n0 + waveN * 64 + ni * 16 + l16;
#pragma unroll
      for (int r = 0; r < 4; r++) {
        const float v = acc[mi][ni][r];
        const size_t row = (size_t)(rowBase + r);
        if constexpr (EPI == 0) {
          c_out[row * (size_t)N + gcol] = v;
        } else if constexpr (EPI == 1) {
          if (gcol < DI) {
            e_bf_a[row * DI + gcol] = f2bf(v);
          } else {
            e_bf1[row * DI + (gcol - DI)] = f2bf(siluf_(v));
          }
        } else {
          const float dt = softplusf_(v + e_v2[gcol]);
          const float a  = __expf(e_v1[gcol] * dt);
          const float xc = bf2f(e_bf2[row * DI + gcol]);
          e_bf_a[row * DI + gcol] = f2bf(xc * dt * a);
          e_bf1[row * DI + gcol] = f2bf(a);
        }
      }
    }
  }
}

// ---------------- depthwise conv1d(k=3,pad=1) + bias + SiLU ----------------------
// works for any row count; batch boundary via l = row & (L_SEQ-1)
__global__ void conv_silu(const u16* __restrict__ xin, const float* __restrict__ cw,
                          const float* __restrict__ cb, u16* __restrict__ xconv_bf) {
  const int idx = blockIdx.x * blockDim.x + threadIdx.x;   // one thread = 4 channels
  const int c4  = (idx % (DI / 4)) * 4;
  const int row = idx / (DI / 4);
  const int l   = row & (L_SEQ - 1);

  const size_t base = (size_t)row * DI + c4;
  u16x4 z4 = {0, 0, 0, 0};
  u16x4 x1 = *(const u16x4*)(xin + base);
  u16x4 x0 = (l > 0)         ? *(const u16x4*)(xin + base - DI) : z4;
  u16x4 x2 = (l < L_SEQ - 1) ? *(const u16x4*)(xin + base + DI) : z4;

  const u16* p0 = (const u16*)&x0;
  const u16* p1 = (const u16*)&x1;
  const u16* p2 = (const u16*)&x2;
  u16x4 o;
  u16* po = (u16*)&o;
#pragma unroll
  for (int j = 0; j < 4; j++) {
    const int c = c4 + j;
    float v = fmaf(cw[c * 3 + 0], bf2f(p0[j]),
              fmaf(cw[c * 3 + 1], bf2f(p1[j]),
                   cw[c * 3 + 2] * bf2f(p2[j]))) + cb[c];
    po[j] = f2bf(siluf_(v));
  }
  *(u16x4*)&xconv_bf[base] = o;
}

// ---------------- chunked prefix scan over L (chunk=128, 32 chunks/batch) --------
#define CHUNK 128
#define NCHUNK (L_SEQ / CHUNK)   // 32

__global__ void scan_partial(const u16* __restrict__ w, float* __restrict__ partial) {
  const int c  = blockIdx.x * 256 + threadIdx.x;   // 0..1535
  const int ch = blockIdx.y;
  const int b  = blockIdx.z;
  size_t base = ((size_t)b * L_SEQ + (size_t)ch * CHUNK) * DI + c;
  float s = 0.0f;
#pragma unroll 4
  for (int i = 0; i < CHUNK; i++) s += bf2f(w[base + (size_t)i * DI]);
  partial[((size_t)b * NCHUNK + ch) * DI + c] = s;
}

__global__ void scan_offsets(float* __restrict__ partial) {
  const int c = blockIdx.x * 256 + threadIdx.x;    // 0..1535
  const int b = blockIdx.z;
  float run = 0.0f;
  for (int ch = 0; ch < NCHUNK; ch++) {
    size_t p = ((size_t)b * NCHUNK + ch) * DI + c;
    float v = partial[p];
    partial[p] = run;
    run += v;
  }
}

// NOTE: ybf aliases aexp (same index read-then-write per thread) — no __restrict__.
__global__ void scan_apply(const u16* __restrict__ w, const float* __restrict__ partial,
                           const u16* aexp, const u16* __restrict__ xconv,
                           const u16* __restrict__ sz, const float* __restrict__ Dp,
                           u16* ybf) {
  const int c  = blockIdx.x * 256 + threadIdx.x;
  const int ch = blockIdx.y;
  const int b  = blockIdx.z;
  float run = partial[((size_t)b * NCHUNK + ch) * DI + c];
  const float dp = Dp[c];
  size_t base = ((size_t)b * L_SEQ + (size_t)ch * CHUNK) * DI + c;
  for (int i = 0; i < CHUNK; i++) {
    size_t p = base + (size_t)i * DI;
    float ae = bf2f(aexp[p]);             // read BEFORE the aliased write
    run += bf2f(w[p]);
    float y = run * ae + bf2f(xconv[p]) * dp;
    y *= bf2f(sz[p]);
    ybf[p] = f2bf(y);
  }
}

// ---------------- launcher ----------------
extern "C" void kernel_launch(void* const* d_in, const int* in_sizes, int n_in,
                              void* d_out, int out_size, void* d_ws, size_t ws_size,
                              hipStream_t stream) {
  const float* x      = (const float*)d_in[0];
  const float* W_in   = (const float*)d_in[1];   // (3072,1024)
  const float* W_out  = (const float*)d_in[2];   // (1024,1536)
  const float* conv_w = (const float*)d_in[3];   // (1536,1,3)
  const float* conv_b = (const float*)d_in[4];
  const float* dt_w   = (const float*)d_in[5];   // (1536,1536)
  const float* dt_b   = (const float*)d_in[6];
  const float* Avec   = (const float*)d_in[7];
  const float* Dp     = (const float*)d_in[8];
  float* out = (float*)d_out;
  char* ws = (char*)d_ws;

  // weights -> bf16 (shared by both paths; layout prefix identical)
  u16* Win_bf  = (u16*)(ws + 0);          //  6,291,456
  u16* dtw_bf  = (u16*)(ws + 6291456);    //  4,718,592
  u16* Wout_bf = (u16*)(ws + 11010048);   //  3,145,728  -> end 14,155,776
  to_bf16<<<3072, 256, 0, stream>>>(W_in,  Win_bf,  786432);
  to_bf16<<<2304, 256, 0, stream>>>(dt_w,  dtw_bf,  589824);
  to_bf16<<<1536, 256, 0, stream>>>(W_out, Wout_bf, 393216);

  const size_t FULL_NEED = 249823232;   // full-batch layout
  if (ws_size >= FULL_NEED) {
    // ---------- full-batch path: M = 16384 ----------
    u16*   x_bf     = (u16*)  (ws + 14155776);    // 33,554,432  (16384x1024)
    u16*   xin_bf   = (u16*)  (ws + 47710208);    // 50,331,648  [w aliases]
    u16*   sz_bf    = (u16*)  (ws + 98041856);    // 50,331,648
    u16*   xconv_bf = (u16*)  (ws + 148373504);   // 50,331,648
    u16*   aexp_bf  = (u16*)  (ws + 198705152);   // 50,331,648  [y aliases]
    float* part     = (float*)(ws + 249036800);   //    786,432  (4x32x1536)
    u16*   w_bf     = xin_bf;
    u16*   y_bf     = aexp_bf;

    to_bf16<<<16384, 256, 0, stream>>>(x, x_bf, 4194304);

    // in_proj GEMM (M=16384, N=3072, K=1024) + split epilogue
    gemm_bt<1><<<dim3(24, 128), 256, 0, stream>>>(x_bf, Win_bf, nullptr,
                                                  2 * DI, DIM_IN,
                                                  xin_bf, sz_bf, nullptr, nullptr, nullptr);
    // depthwise conv + SiLU (batch edges via l = row & 4095)
    conv_silu<<<24576, 256, 0, stream>>>(xin_bf, conv_w, conv_b, xconv_bf);

    // dt GEMM (M=16384, N=1536, K=1536) + softplus/exp/w epilogue
    gemm_bt<2><<<dim3(12, 128), 256, 0, stream>>>(xconv_bf, dtw_bf, nullptr,
                                                  DI, DI,
                                                  w_bf, aexp_bf, xconv_bf, Avec, dt_b);

    // chunked prefix scan + pointwise tail
    scan_partial<<<dim3(6, NCHUNK, BATCH), 256, 0, stream>>>(w_bf, part);
    scan_offsets<<<dim3(6, 1, BATCH), 256, 0, stream>>>(part);
    scan_apply<<<dim3(6, NCHUNK, BATCH), 256, 0, stream>>>(w_bf, part, aexp_bf,
                                                           xconv_bf, sz_bf, Dp, y_bf);

    // out_proj GEMM (M=16384, N=1024, K=1536) -> fp32 output
    gemm_bt<0><<<dim3(8, 128), 256, 0, stream>>>(y_bf, Wout_bf, out,
                                                 DIM_IN, DI,
                                                 nullptr, nullptr, nullptr, nullptr, nullptr);
    return;
  }

  // ---------- per-batch fallback (round-2 proven path, 73 MB) ----------
  const size_t WS_NEED = 73072640;
  if (ws_size < WS_NEED) return;   // diagnostic: absmax=2096 w/o crash => ws too small

  u16*   x_bf     = (u16*)  (ws + 14155776);   //  8,388,608   (4096x1024)
  u16*   xin_bf   = (u16*)  (ws + 22544384);   // 12,582,912   [w aliases]
  u16*   sz_bf    = (u16*)  (ws + 35127296);   // 12,582,912
  u16*   xconv_bf = (u16*)  (ws + 47710208);   // 12,582,912
  u16*   aexp_bf  = (u16*)  (ws + 60293120);   // 12,582,912   [y aliases]
  float* part     = (float*)(ws + 72876032);   //    196,608
  u16*   w_bf     = xin_bf;
  u16*   y_bf     = aexp_bf;

  for (int b = 0; b < BATCH; b++) {
    const float* xb   = x   + (size_t)b * L_SEQ * DIM_IN;
    float*       outb = out + (size_t)b * L_SEQ * DIM_IN;

    to_bf16<<<4096, 256, 0, stream>>>(xb, x_bf, 1048576);
    gemm_bt<1><<<dim3(24, 32), 256, 0, stream>>>(x_bf, Win_bf, nullptr,
                                                 2 * DI, DIM_IN,
                                                 xin_bf, sz_bf, nullptr, nullptr, nullptr);
    conv_silu<<<6144, 256, 0, stream>>>(xin_bf, conv_w, conv_b, xconv_bf);
    gemm_bt<2><<<dim3(12, 32), 256, 0, stream>>>(xconv_bf, dtw_bf, nullptr,
                                                 DI, DI,
                                                 w_bf, aexp_bf, xconv_bf, Avec, dt_b);
    scan_partial<<<dim3(6, NCHUNK, 1), 256, 0, stream>>>(w_bf, part);
    scan_offsets<<<dim3(6, 1, 1), 256, 0, stream>>>(part);
    scan_apply<<<dim3(6, NCHUNK, 1), 256, 0, stream>>>(w_bf, part, aexp_bf,
                                                       xconv_bf, sz_bf, Dp, y_bf);
    gemm_bt<0><<<dim3(8, 32), 256, 0, stream>>>(y_bf, Wout_bf, outb,
                                                DIM_IN, DI,
                                                nullptr, nullptr, nullptr, nullptr, nullptr);
  }
}